// Round 11
// baseline (3853.077 us; speedup 1.0000x reference)
//
#include <hip/hip_runtime.h>
#include <hip/hip_fp16.h>
#include <cstdint>
#include <cstddef>

#define D_MODEL 512
#define N_HEADS 8
#define HEAD_E  64
#define SEQ_L   2048
#define BATCH   2
#define KSEL    38            // int(5*log(2048)) = 38
#define M_ROWS  (BATCH*SEQ_L) // 4096
#define SP      2050          // S row stride (f16)
#define CCAP    192           // candidate cap (3 per lane); overflow -> fixup

typedef short bf16x8 __attribute__((ext_vector_type(8)));
typedef float f32x4  __attribute__((ext_vector_type(4)));

static __device__ __forceinline__ unsigned short f2bf(float x) {
  uint32_t u = __float_as_uint(x);
  return (unsigned short)((u + 0x7FFF + ((u >> 16) & 1)) >> 16);  // RNE
}

// ---------------------------------------------------------------------------
// Fused QKV f32 GEMM: z=0:Q, z=1:K, z=2:V. C = x @ W.T + b. Q,K emit bf16 too.
// ---------------------------------------------------------------------------
__global__ __launch_bounds__(256) void gemm_qkv_kernel(
    const float* __restrict__ A,
    const float* __restrict__ Wq, const float* __restrict__ bq,
    const float* __restrict__ Wk, const float* __restrict__ bk,
    const float* __restrict__ Wv, const float* __restrict__ bv,
    float* __restrict__ Qf, float* __restrict__ Kf, float* __restrict__ Vf,
    unsigned short* __restrict__ Qh, unsigned short* __restrict__ Kh)
{
  const int z = blockIdx.z;
  const float* W    = (z == 0) ? Wq : ((z == 1) ? Wk : Wv);
  const float* bias = (z == 0) ? bq : ((z == 1) ? bk : bv);
  float* C          = (z == 0) ? Qf : ((z == 1) ? Kf : Vf);
  unsigned short* Ch = (z == 0) ? Qh : ((z == 1) ? Kh : nullptr);

  __shared__ float As[64][36];
  __shared__ float Ws[64][36];
  const int t  = threadIdx.x;
  const int tx = t & 15, ty = t >> 4;
  const int bm = blockIdx.y << 6, bn = blockIdx.x << 6;

  float acc[4][4] = {};

  for (int k0 = 0; k0 < D_MODEL; k0 += 32) {
    __syncthreads();
#pragma unroll
    for (int i = 0; i < 2; ++i) {
      int f = t + (i << 8);
      int r = f >> 3, c = (f & 7) << 2;
      *(float4*)&As[r][c] = *(const float4*)&A[(size_t)(bm + r) * D_MODEL + k0 + c];
      *(float4*)&Ws[r][c] = *(const float4*)&W[(size_t)(bn + r) * D_MODEL + k0 + c];
    }
    __syncthreads();
#pragma unroll
    for (int kk = 0; kk < 32; kk += 4) {
      float4 av[4], wv[4];
#pragma unroll
      for (int i = 0; i < 4; ++i) av[i] = *(const float4*)&As[ty * 4 + i][kk];
#pragma unroll
      for (int j = 0; j < 4; ++j) wv[j] = *(const float4*)&Ws[tx + 16 * j][kk];
#pragma unroll
      for (int i = 0; i < 4; ++i)
#pragma unroll
        for (int j = 0; j < 4; ++j)
          acc[i][j] += av[i].x * wv[j].x + av[i].y * wv[j].y +
                       av[i].z * wv[j].z + av[i].w * wv[j].w;
    }
  }

#pragma unroll
  for (int i = 0; i < 4; ++i) {
    int row = bm + ty * 4 + i;
#pragma unroll
    for (int j = 0; j < 4; ++j) {
      int col = bn + tx + 16 * j;
      float v = acc[i][j] + bias[col];
      size_t idx = (size_t)row * D_MODEL + col;
      C[idx] = v;
      if (Ch) Ch[idx] = f2bf(v);
    }
  }
}

// ---------------------------------------------------------------------------
// f32 GEMM (output projection): C = A @ W.T + b
// ---------------------------------------------------------------------------
__global__ __launch_bounds__(256) void gemm_bias_kernel(
    const float* __restrict__ A, const float* __restrict__ W,
    const float* __restrict__ bias, float* __restrict__ C,
    int M, int N, int K)
{
  __shared__ float As[64][36];
  __shared__ float Ws[64][36];
  const int t  = threadIdx.x;
  const int tx = t & 15, ty = t >> 4;
  const int bm = blockIdx.y << 6, bn = blockIdx.x << 6;

  float acc[4][4] = {};

  for (int k0 = 0; k0 < K; k0 += 32) {
    __syncthreads();
#pragma unroll
    for (int i = 0; i < 2; ++i) {
      int f = t + (i << 8);
      int r = f >> 3, c = (f & 7) << 2;
      *(float4*)&As[r][c] = *(const float4*)&A[(size_t)(bm + r) * K + k0 + c];
      *(float4*)&Ws[r][c] = *(const float4*)&W[(size_t)(bn + r) * K + k0 + c];
    }
    __syncthreads();
#pragma unroll
    for (int kk = 0; kk < 32; kk += 4) {
      float4 av[4], wv[4];
#pragma unroll
      for (int i = 0; i < 4; ++i) av[i] = *(const float4*)&As[ty * 4 + i][kk];
#pragma unroll
      for (int j = 0; j < 4; ++j) wv[j] = *(const float4*)&Ws[tx + 16 * j][kk];
#pragma unroll
      for (int i = 0; i < 4; ++i)
#pragma unroll
        for (int j = 0; j < 4; ++j)
          acc[i][j] += av[i].x * wv[j].x + av[i].y * wv[j].y +
                       av[i].z * wv[j].z + av[i].w * wv[j].w;
    }
  }

#pragma unroll
  for (int i = 0; i < 4; ++i) {
    int row = bm + ty * 4 + i;
#pragma unroll
    for (int j = 0; j < 4; ++j) {
      int col = bn + tx + 16 * j;
      C[(size_t)row * N + col] = acc[i][j] + bias[col];
    }
  }
}

// ---------------------------------------------------------------------------
// Per-(b,h,e) max |K_e| over keys — feeds the provable bf16-error margin.
// ---------------------------------------------------------------------------
__global__ __launch_bounds__(256) void kemax_kernel(
    const float* __restrict__ Kf, float* __restrict__ kemax)
{
  const int bh = blockIdx.x;
  const int b = bh >> 3, h = bh & 7;
  const int e = threadIdx.x & 63, chunk = threadIdx.x >> 6;
  const float* base = Kf + ((size_t)b * SEQ_L) * D_MODEL + h * HEAD_E + e;
  float mx = 0.f;
  for (int k = chunk * 512; k < chunk * 512 + 512; ++k)
    mx = fmaxf(mx, fabsf(base[(size_t)k * D_MODEL]));
  __shared__ float red[4][64];
  red[chunk][e] = mx;
  __syncthreads();
  if (threadIdx.x < 64) {
    float m0 = fmaxf(fmaxf(red[0][threadIdx.x], red[1][threadIdx.x]),
                     fmaxf(red[2][threadIdx.x], red[3][threadIdx.x]));
    kemax[bh * 64 + threadIdx.x] = m0;
  }
}

// ---------------------------------------------------------------------------
// Main ProbSparse attention v11 — LEAN path only.
// MFMA bf16 scan -> one-shot Gaussian threshold (mu + 1.707*sigma, targets
// count~90) + ONE verify countge -> provable-margin capture -> exact f32
// rescore (3/lane) -> exact bisect to [40,64] -> compact -> bitonic ->
// gap>=2e-5 -> f32 softmax + PV.
// ALL rare cases (count not in [40,176], capture>CCAP, tight gap) are
// flagged to an atomic list and fully handled by attn_fixup.
// ---------------------------------------------------------------------------
__global__ __launch_bounds__(512) void attn_main(
    const float* __restrict__ Qf, const float* __restrict__ Kf,
    const float* __restrict__ Vf,
    const unsigned short* __restrict__ Qh, const unsigned short* __restrict__ Kh,
    const float* __restrict__ kemax, float* __restrict__ AO,
    int* __restrict__ nflag, int* __restrict__ flagged)
{
  __shared__ __half  S[16][SP];          // 65600 B approx scores
  __shared__ short   cis2[8][CCAP];      // captured candidate indices
  __shared__ float   cvs[8][64];         // exact candidates (post bisect)
  __shared__ short   cis[8][64];
  __shared__ float   qrowL[16][64];      // f32 q rows (hoisted)
  __shared__ float   kemaxL[64];

  const int t    = threadIdx.x;
  const int w    = t >> 6;
  const int l    = t & 63;

  // XCD-affine decode
  const int wg   = blockIdx.x;
  const int xcd  = wg & 7;
  const int idx  = wg >> 3;
  const int bh   = xcd + 8 * (idx >> 7);
  const int qblk = idx & 127;
  const int b    = bh >> 3, h = bh & 7;
  const int q0   = qblk << 4;
  const size_t rowbase = (size_t)b * SEQ_L;

  if (t < 64) kemaxL[t] = kemax[bh * 64 + t];

  // hoist both q-row loads (latency overlaps the MFMA scan)
  {
    const float* qb = Qf + (rowbase + q0 + 2 * w) * D_MODEL + h * HEAD_E;
    qrowL[2 * w][l]     = qb[l];
    qrowL[2 * w + 1][l] = qb[D_MODEL + l];
  }

  // ---- MFMA score scan: wave w covers keys [w*256, w*256+256) ----
  {
    const int lo16 = l & 15, grp = l >> 4;
    const unsigned short* qrow =
        Qh + (rowbase + q0 + lo16) * D_MODEL + h * HEAD_E;
    bf16x8 a0 = *(const bf16x8*)&qrow[grp * 8];
    bf16x8 a1 = *(const bf16x8*)&qrow[32 + grp * 8];

    const int kbase = w * 256;
#pragma unroll
    for (int kt = 0; kt < 4; ++kt) {
#pragma unroll
      for (int kc = 0; kc < 4; ++kc) {
        const int key0 = kbase + kt * 64 + kc * 16 + lo16;
        const unsigned short* krow =
            Kh + (rowbase + key0) * D_MODEL + h * HEAD_E;
        bf16x8 b0 = *(const bf16x8*)&krow[grp * 8];
        bf16x8 b1 = *(const bf16x8*)&krow[32 + grp * 8];
        f32x4 acc = {0.f, 0.f, 0.f, 0.f};
        acc = __builtin_amdgcn_mfma_f32_16x16x32_bf16(a0, b0, acc, 0, 0, 0);
        acc = __builtin_amdgcn_mfma_f32_16x16x32_bf16(a1, b1, acc, 0, 0, 0);
#pragma unroll
        for (int r = 0; r < 4; ++r)
          S[grp * 4 + r][key0] = __float2half(acc[r] * 0.125f);
      }
    }
  }
  __syncthreads();

  // ---- selection: wave w handles queries 2w, 2w+1 ----
  for (int qq = 0; qq < 2; ++qq) {
    const int q   = 2 * w + qq;
    const int qid = bh * SEQ_L + q0 + q;

    float v[32];
#pragma unroll
    for (int j = 0; j < 32; ++j) v[j] = __half2float(S[q][(j << 6) + l]);

    // fused max / mean / var reduce
    float m = v[0], s1 = 0.f, s2 = 0.f;
#pragma unroll
    for (int j = 0; j < 32; ++j) {
      m = fmaxf(m, v[j]); s1 += v[j]; s2 += v[j] * v[j];
    }
#pragma unroll
    for (int off = 1; off < 64; off <<= 1) {
      m  = fmaxf(m, __shfl_xor(m, off));
      s1 += __shfl_xor(s1, off);
      s2 += __shfl_xor(s2, off);
    }
    const float mu = s1 * (1.0f / 2048.0f);
    const float sg = sqrtf(fmaxf(s2 * (1.0f / 2048.0f) - mu * mu, 0.f));
    const float lo = mu + 1.707f * sg;   // targets count ~ 90

    // ONE verify countge
    int C = 0;
#pragma unroll
    for (int j = 0; j < 32; ++j) C += (v[j] >= lo) ? 1 : 0;
#pragma unroll
    for (int off = 1; off < 64; off <<= 1) C += __shfl_xor(C, off);

    bool punt = (C < 40) | (C > 176);
    int base = 0;
    if (!punt) {
      // provable margin capture (unchanged constants)
      float red = fabsf(qrowL[q][l]) * kemaxL[l];
#pragma unroll
      for (int off = 1; off < 64; off <<= 1) red += __shfl_xor(red, off);
      const float lo2 = lo - (red * 0.0025f + 0.008f);
#pragma unroll
      for (int j = 0; j < 32; ++j) {
        bool in = (v[j] >= lo2);
        unsigned long long mk = __ballot(in);
        if (in) {
          int pos = base + (int)__popcll(mk & ((1ull << l) - 1ull));
          if (pos < CCAP) cis2[w][pos] = (short)((j << 6) | l);
        }
        base += (int)__popcll(mk);
      }
      punt = (base > CCAP);
    }
    if (punt) {
      if (l == 0) { int p = atomicAdd(nflag, 1); flagged[p] = qid; }
      continue;
    }

    // ---- exact f32 rescore of captured candidates (3 per lane) ----
    const int count2 = base;
    const int i0 = l, i1 = 64 + l, i2 = 128 + l;
    const int idx0 = (i0 < count2) ? (int)cis2[w][i0] : 0;
    const int idx1 = (i1 < count2) ? (int)cis2[w][i1] : 0;
    const int idx2 = (i2 < count2) ? (int)cis2[w][i2] : 0;
    float e0 = -3.0e38f, e1 = -3.0e38f, e2 = -3.0e38f;
    {
      const float* kr0 = Kf + (rowbase + idx0) * D_MODEL + h * HEAD_E;
      const float* kr1 = Kf + (rowbase + idx1) * D_MODEL + h * HEAD_E;
      const float* kr2 = Kf + (rowbase + idx2) * D_MODEL + h * HEAD_E;
      float r0 = 0.f, r1 = 0.f, r2 = 0.f;
#pragma unroll
      for (int e4 = 0; e4 < 16; ++e4) {
        float4 qv = *(const float4*)&qrowL[q][e4 * 4];
        float4 k0 = *(const float4*)&kr0[e4 * 4];
        float4 k1 = *(const float4*)&kr1[e4 * 4];
        float4 k2 = *(const float4*)&kr2[e4 * 4];
        r0 += qv.x * k0.x + qv.y * k0.y + qv.z * k0.z + qv.w * k0.w;
        r1 += qv.x * k1.x + qv.y * k1.y + qv.z * k1.z + qv.w * k1.w;
        r2 += qv.x * k2.x + qv.y * k2.y + qv.z * k2.z + qv.w * k2.w;
      }
      if (i0 < count2) e0 = r0 * 0.125f;
      if (i1 < count2) e1 = r1 * 0.125f;
      if (i2 < count2) e2 = r2 * 0.125f;
    }

    // exact bisect to count in [40, 64]
    float hiv = fmaxf(fmaxf(e0, e1), e2);
    float lov = fminf(fminf((i0 < count2) ? e0 : 3.0e38f,
                            (i1 < count2) ? e1 : 3.0e38f),
                            (i2 < count2) ? e2 : 3.0e38f);
#pragma unroll
    for (int off = 1; off < 64; off <<= 1) {
      hiv = fmaxf(hiv, __shfl_xor(hiv, off));
      lov = fminf(lov, __shfl_xor(lov, off));
    }
    lov -= 1e-3f;
    for (int it = 0; it < 30; ++it) {
      int c = (int)__popcll(__ballot(e0 >= lov)) +
              (int)__popcll(__ballot(e1 >= lov)) +
              (int)__popcll(__ballot(e2 >= lov));
      if (c <= 64) break;
      float mid = 0.5f * (lov + hiv);
      int cm = (int)__popcll(__ballot(e0 >= mid)) +
               (int)__popcll(__ballot(e1 >= mid)) +
               (int)__popcll(__ballot(e2 >= mid));
      if (cm >= 40) lov = mid; else hiv = mid;
    }

    // compact exact-selected into cvs/cis (key order preserved)
    int C2;
    {
      bool in0 = (e0 >= lov);
      bool in1 = (e1 >= lov);
      bool in2 = (e2 >= lov);
      unsigned long long m0 = __ballot(in0);
      unsigned long long m1 = __ballot(in1);
      unsigned long long m2 = __ballot(in2);
      int tot0 = (int)__popcll(m0), tot1 = (int)__popcll(m1);
      if (in0) {
        int p = (int)__popcll(m0 & ((1ull << l) - 1ull));
        if (p < 64) { cvs[w][p] = e0; cis[w][p] = (short)idx0; }
      }
      if (in1) {
        int p = tot0 + (int)__popcll(m1 & ((1ull << l) - 1ull));
        if (p < 64) { cvs[w][p] = e1; cis[w][p] = (short)idx1; }
      }
      if (in2) {
        int p = tot0 + tot1 + (int)__popcll(m2 & ((1ull << l) - 1ull));
        if (p < 64) { cvs[w][p] = e2; cis[w][p] = (short)idx2; }
      }
      int tot = tot0 + tot1 + (int)__popcll(m2);
      C2 = (tot < 64) ? tot : 64;
    }

    float cval = (l < C2) ? cvs[w][l] : -3.0e38f;
    int   cidx = (l < C2) ? (int)cis[w][l] : (2 * SEQ_L + l);

    // bitonic sort 64: value desc, index asc
#pragma unroll
    for (int sz = 2; sz <= 64; sz <<= 1) {
#pragma unroll
      for (int st = sz >> 1; st >= 1; st >>= 1) {
        float ov = __shfl_xor(cval, st);
        int   oi = __shfl_xor(cidx, st);
        bool ob    = (ov > cval) || ((ov == cval) && (oi < cidx));
        bool dir   = ((l & sz) == 0);
        bool lower = ((l & st) == 0);
        if (ob == (lower == dir)) { cval = ov; cidx = oi; }
      }
    }

    const float m_ex = __shfl(cval, 0);
    const float v37  = __shfl(cval, 37);
    const float v38  = __shfl(cval, 38);
    if (v37 - v38 < 2e-5f) {           // tight boundary -> fixup
      if (l == 0) { int p = atomicAdd(nflag, 1); flagged[p] = qid; }
      continue;
    }

    float myw = (l < KSEL) ? __expf(cval - m_ex) : 0.f;
    float psum = myw;
#pragma unroll
    for (int off = 1; off < 64; off <<= 1) psum += __shfl_xor(psum, off);
    const float inv = 1.0f / psum;

    // ---- PV: branchless, 8 gather loads in flight per batch ----
    const float* Vb = Vf + rowbase * D_MODEL + h * HEAD_E;
    float acc = 0.f;
    for (int j0 = 0; j0 < 40; j0 += 8) {
      float wv8[8]; const float* vp8[8];
#pragma unroll
      for (int u = 0; u < 8; ++u) {
        wv8[u] = __shfl(myw, j0 + u);
        int sj = __shfl(cidx, j0 + u) & (SEQ_L - 1);
        vp8[u] = Vb + (size_t)sj * D_MODEL + l;
      }
      float vv8[8];
#pragma unroll
      for (int u = 0; u < 8; ++u) vv8[u] = *vp8[u];
#pragma unroll
      for (int u = 0; u < 8; ++u) acc = fmaf(wv8[u], vv8[u], acc);
    }
    AO[(rowbase + q0 + q) * D_MODEL + h * HEAD_E + l] = acc * inv;
  }
}

// ---------------------------------------------------------------------------
// Fixup: full exact handling of flagged queries (~1-2%). One wave per query.
// Full exact-f32 rescan of 2048 keys -> bisect to [40,64] -> f64 rescore of
// candidates (on the fly from x,Wq,Wk — R8-proven math) -> exact f64 top-38
// -> softmax -> PV -> overwrite AO row.
// ---------------------------------------------------------------------------
__global__ __launch_bounds__(64) void attn_fixup(
    const float* __restrict__ Qf, const float* __restrict__ Kf,
    const float* __restrict__ Vf,
    const float* __restrict__ x,
    const float* __restrict__ Wq, const float* __restrict__ bq,
    const float* __restrict__ Wk, const float* __restrict__ bk,
    float* __restrict__ AO,
    const int* __restrict__ nflag, const int* __restrict__ flagged)
{
  __shared__ float qr[64];
  __shared__ float cv[64];
  __shared__ int   ci[64];

  const int l = threadIdx.x;
  const int n = *nflag;

  for (int s = blockIdx.x; s < n; s += gridDim.x) {
    const int qid  = flagged[s];
    const int bh   = qid >> 11, qrow = qid & (SEQ_L - 1);
    const int b    = bh >> 3, h = bh & 7;
    const size_t rowbase = (size_t)b * SEQ_L;

    qr[l] = Qf[(rowbase + qrow) * D_MODEL + h * HEAD_E + l];
    __syncthreads();

    // exact f32 scores for all 2048 keys (32 per lane)
    float v[32];
#pragma unroll 4
    for (int j = 0; j < 32; ++j) {
      const float* kr = Kf + (rowbase + (j << 6) + l) * D_MODEL + h * HEAD_E;
      float r0 = 0.f, r1 = 0.f;
#pragma unroll
      for (int e4 = 0; e4 < 16; e4 += 2) {
        float4 qv0 = *(const float4*)&qr[e4 * 4];
        float4 qv1 = *(const float4*)&qr[e4 * 4 + 4];
        float4 k0 = *(const float4*)&kr[e4 * 4];
        float4 k1 = *(const float4*)&kr[e4 * 4 + 4];
        r0 += qv0.x * k0.x + qv0.y * k0.y + qv0.z * k0.z + qv0.w * k0.w;
        r1 += qv1.x * k1.x + qv1.y * k1.y + qv1.z * k1.z + qv1.w * k1.w;
      }
      v[j] = (r0 + r1) * 0.125f;
    }

    auto countge = [&](float T) -> int {
      int c = 0;
#pragma unroll
      for (int j = 0; j < 32; ++j) c += (v[j] >= T) ? 1 : 0;
#pragma unroll
      for (int off = 1; off < 64; off <<= 1) c += __shfl_xor(c, off);
      return c;
    };

    // bisect to count in [40, 64]
    float hiv = v[0], lov = v[0];
#pragma unroll
    for (int j = 1; j < 32; ++j) { hiv = fmaxf(hiv, v[j]); lov = fminf(lov, v[j]); }
#pragma unroll
    for (int off = 1; off < 64; off <<= 1) {
      hiv = fmaxf(hiv, __shfl_xor(hiv, off));
      lov = fminf(lov, __shfl_xor(lov, off));
    }
    lov -= 1e-3f;
    for (int it = 0; it < 30; ++it) {
      int c = countge(lov);
      if (c <= 64) break;
      float mid = 0.5f * (lov + hiv);
      int cm = countge(mid);
      if (cm >= 40) lov = mid; else hiv = mid;
    }

    // compact candidates (key order), cap 64
    int bb = 0;
#pragma unroll
    for (int j = 0; j < 32; ++j) {
      bool in = (v[j] >= lov);
      unsigned long long mk = __ballot(in);
      if (in) {
        int pos = bb + (int)__popcll(mk & ((1ull << l) - 1ull));
        if (pos < 64) { cv[pos] = v[j]; ci[pos] = (j << 6) + l; }
      }
      bb += (int)__popcll(mk);
    }
    const int C2 = (bb < 64) ? bb : 64;
    __syncthreads();
    const int cidx = (l < C2) ? ci[l] : (2 * SEQ_L + l);

    // ---- exact f64 rescore (shuffle-only, from x/Wq/Wk) ----
    const int he = h * HEAD_E + l;
    const float* wqr = Wq + (size_t)he * D_MODEL;
    const float* xr  = x + (rowbase + qrow) * D_MODEL;
    double qa0 = 0.0, qa1 = 0.0, qa2 = 0.0, qa3 = 0.0;
    for (int j = 0; j < D_MODEL; j += 4) {
      float4 wq4 = *(const float4*)&wqr[j];
      float4 x4  = *(const float4*)&xr[j];
      qa0 += (double)wq4.x * (double)x4.x;
      qa1 += (double)wq4.y * (double)x4.y;
      qa2 += (double)wq4.z * (double)x4.z;
      qa3 += (double)wq4.w * (double)x4.w;
    }
    double qd = ((qa0 + qa1) + (qa2 + qa3)) + (double)bq[he];

    double qkb = qd * (double)bk[he];
#pragma unroll
    for (int off = 1; off < 64; off <<= 1) qkb += __shfl_xor(qkb, off);

    const int crow = (l < C2) ? cidx : 0;
    const float* xc = x + (rowbase + crow) * D_MODEL;
    double s_c = qkb;
    for (int jc = 0; jc < 8; ++jc) {
      const float* wkc = Wk + (jc << 6) + l;
      double u0 = 0.0, u1 = 0.0;
      for (int e = 0; e < 64; e += 2) {
        double qde0 = __shfl(qd, e);
        double qde1 = __shfl(qd, e + 1);
        u0 += qde0 * (double)wkc[(size_t)(h * HEAD_E + e) * D_MODEL];
        u1 += qde1 * (double)wkc[(size_t)(h * HEAD_E + e + 1) * D_MODEL];
      }
      double uacc = u0 + u1;
      double s0 = 0.0, s1 = 0.0;
      for (int jj = 0; jj < 64; jj += 2) {
        double uj0 = __shfl(uacc, jj);
        double uj1 = __shfl(uacc, jj + 1);
        s0 += uj0 * (double)xc[(jc << 6) + jj];
        s1 += uj1 * (double)xc[(jc << 6) + jj + 1];
      }
      s_c += s0 + s1;
    }
    double d = (l < C2) ? s_c * 0.125 : -1.0e300;
    int myi = (l < C2) ? cidx : (2 * SEQ_L + l);
    double mxd = -1.0e300; int rank = 0;
    for (int j = 0; j < 64; ++j) {
      double dj = __shfl(d, j);
      int    ij = __shfl(myi, j);
      if (dj > mxd) mxd = dj;
      rank += (dj > d) || ((dj == d) && (ij < myi));
    }
    float myw = (l < C2 && rank < KSEL) ? __expf((float)(d - mxd)) : 0.f;

    float psum = myw;
#pragma unroll
    for (int off = 1; off < 64; off <<= 1) psum += __shfl_xor(psum, off);
    const float inv = 1.0f / psum;

    // PV
    const float* Vb = Vf + rowbase * D_MODEL + h * HEAD_E;
    float acc = 0.f;
    for (int j0 = 0; j0 < 64; j0 += 8) {
      float wv8[8]; const float* vp8[8];
#pragma unroll
      for (int u = 0; u < 8; ++u) {
        wv8[u] = __shfl(myw, j0 + u);
        int sj = __shfl(cidx, j0 + u) & (SEQ_L - 1);
        vp8[u] = Vb + (size_t)sj * D_MODEL + l;
      }
      float vv8[8];
#pragma unroll
      for (int u = 0; u < 8; ++u) vv8[u] = *vp8[u];
#pragma unroll
      for (int u = 0; u < 8; ++u) acc = fmaf(wv8[u], vv8[u], acc);
    }
    AO[(rowbase + qrow) * D_MODEL + h * HEAD_E + l] = acc * inv;
    __syncthreads();   // protect qr/cv/ci before next iteration
  }
}

// ---------------------------------------------------------------------------
extern "C" void kernel_launch(void* const* d_in, const int* in_sizes, int n_in,
                              void* d_out, int out_size, void* d_ws, size_t ws_size,
                              hipStream_t stream) {
  const float* x  = (const float*)d_in[0];
  const float* Wq = (const float*)d_in[1];
  const float* bq = (const float*)d_in[2];
  const float* Wk = (const float*)d_in[3];
  const float* bk = (const float*)d_in[4];
  const float* Wv = (const float*)d_in[5];
  const float* bv = (const float*)d_in[6];
  const float* Wo = (const float*)d_in[7];
  const float* bo = (const float*)d_in[8];
  float* out = (float*)d_out;

  char* ws = (char*)d_ws;
  const size_t MATB = (size_t)M_ROWS * D_MODEL * 4;  // 8 MB
  float* Qf = (float*)ws;
  float* Kf = (float*)(ws + MATB);
  float* Vf = (float*)(ws + 2 * MATB);
  float* AO = (float*)(ws + 3 * MATB);
  unsigned short* Qh = (unsigned short*)(ws + 4 * MATB);            // 4 MB
  unsigned short* Kh = (unsigned short*)(ws + 4 * MATB + MATB / 2); // 4 MB
  float* kemax = (float*)(ws + 5 * MATB);                           // 4 KB
  int* nflag   = (int*)(ws + 5 * MATB + 4096);
  int* flagged = (int*)(ws + 5 * MATB + 8192);                      // 128 KB

  hipMemsetAsync(nflag, 0, 64, stream);

  dim3 qkvgrid(D_MODEL / 64, M_ROWS / 64, 3);
  gemm_qkv_kernel<<<qkvgrid, 256, 0, stream>>>(
      x, Wq, bq, Wk, bk, Wv, bv, Qf, Kf, Vf, Qh, Kh);

  kemax_kernel<<<dim3(BATCH * N_HEADS), 256, 0, stream>>>(Kf, kemax);

  attn_main<<<dim3(SEQ_L / 16 * BATCH * N_HEADS), 512, 0, stream>>>(
      Qf, Kf, Vf, Qh, Kh, kemax, AO, nflag, flagged);

  attn_fixup<<<dim3(2048), 64, 0, stream>>>(
      Qf, Kf, Vf, x, Wq, bq, Wk, bk, AO, nflag, flagged);

  dim3 ggrid(D_MODEL / 64, M_ROWS / 64);
  gemm_bias_kernel<<<ggrid, 256, 0, stream>>>(AO, Wo, bo, out, M_ROWS, D_MODEL, D_MODEL);
}

// Round 12
// 1243.620 us; speedup vs baseline: 3.0983x; 3.0983x over previous
//
#include <hip/hip_runtime.h>
#include <hip/hip_fp16.h>
#include <cstdint>
#include <cstddef>

#define D_MODEL 512
#define N_HEADS 8
#define HEAD_E  64
#define SEQ_L   2048
#define BATCH   2
#define KSEL    38            // int(5*log(2048)) = 38
#define M_ROWS  (BATCH*SEQ_L) // 4096
#define SP      2050          // S row stride (f16)
#define CCAP    192           // candidate cap (3 per lane); overflow -> fixup

typedef short bf16x8 __attribute__((ext_vector_type(8)));
typedef float f32x4  __attribute__((ext_vector_type(4)));

static __device__ __forceinline__ unsigned short f2bf(float x) {
  uint32_t u = __float_as_uint(x);
  return (unsigned short)((u + 0x7FFF + ((u >> 16) & 1)) >> 16);  // RNE
}

// ---------------------------------------------------------------------------
// Fused QKV f32 GEMM: z=0:Q, z=1:K, z=2:V. C = x @ W.T + b. Q,K emit bf16 too.
// ---------------------------------------------------------------------------
__global__ __launch_bounds__(256) void gemm_qkv_kernel(
    const float* __restrict__ A,
    const float* __restrict__ Wq, const float* __restrict__ bq,
    const float* __restrict__ Wk, const float* __restrict__ bk,
    const float* __restrict__ Wv, const float* __restrict__ bv,
    float* __restrict__ Qf, float* __restrict__ Kf, float* __restrict__ Vf,
    unsigned short* __restrict__ Qh, unsigned short* __restrict__ Kh)
{
  const int z = blockIdx.z;
  const float* W    = (z == 0) ? Wq : ((z == 1) ? Wk : Wv);
  const float* bias = (z == 0) ? bq : ((z == 1) ? bk : bv);
  float* C          = (z == 0) ? Qf : ((z == 1) ? Kf : Vf);
  unsigned short* Ch = (z == 0) ? Qh : ((z == 1) ? Kh : nullptr);

  __shared__ float As[64][36];
  __shared__ float Ws[64][36];
  const int t  = threadIdx.x;
  const int tx = t & 15, ty = t >> 4;
  const int bm = blockIdx.y << 6, bn = blockIdx.x << 6;

  float acc[4][4] = {};

  for (int k0 = 0; k0 < D_MODEL; k0 += 32) {
    __syncthreads();
#pragma unroll
    for (int i = 0; i < 2; ++i) {
      int f = t + (i << 8);
      int r = f >> 3, c = (f & 7) << 2;
      *(float4*)&As[r][c] = *(const float4*)&A[(size_t)(bm + r) * D_MODEL + k0 + c];
      *(float4*)&Ws[r][c] = *(const float4*)&W[(size_t)(bn + r) * D_MODEL + k0 + c];
    }
    __syncthreads();
#pragma unroll
    for (int kk = 0; kk < 32; kk += 4) {
      float4 av[4], wv[4];
#pragma unroll
      for (int i = 0; i < 4; ++i) av[i] = *(const float4*)&As[ty * 4 + i][kk];
#pragma unroll
      for (int j = 0; j < 4; ++j) wv[j] = *(const float4*)&Ws[tx + 16 * j][kk];
#pragma unroll
      for (int i = 0; i < 4; ++i)
#pragma unroll
        for (int j = 0; j < 4; ++j)
          acc[i][j] += av[i].x * wv[j].x + av[i].y * wv[j].y +
                       av[i].z * wv[j].z + av[i].w * wv[j].w;
    }
  }

#pragma unroll
  for (int i = 0; i < 4; ++i) {
    int row = bm + ty * 4 + i;
#pragma unroll
    for (int j = 0; j < 4; ++j) {
      int col = bn + tx + 16 * j;
      float v = acc[i][j] + bias[col];
      size_t idx = (size_t)row * D_MODEL + col;
      C[idx] = v;
      if (Ch) Ch[idx] = f2bf(v);
    }
  }
}

// ---------------------------------------------------------------------------
// f32 GEMM (output projection): C = A @ W.T + b
// ---------------------------------------------------------------------------
__global__ __launch_bounds__(256) void gemm_bias_kernel(
    const float* __restrict__ A, const float* __restrict__ W,
    const float* __restrict__ bias, float* __restrict__ C,
    int M, int N, int K)
{
  __shared__ float As[64][36];
  __shared__ float Ws[64][36];
  const int t  = threadIdx.x;
  const int tx = t & 15, ty = t >> 4;
  const int bm = blockIdx.y << 6, bn = blockIdx.x << 6;

  float acc[4][4] = {};

  for (int k0 = 0; k0 < K; k0 += 32) {
    __syncthreads();
#pragma unroll
    for (int i = 0; i < 2; ++i) {
      int f = t + (i << 8);
      int r = f >> 3, c = (f & 7) << 2;
      *(float4*)&As[r][c] = *(const float4*)&A[(size_t)(bm + r) * K + k0 + c];
      *(float4*)&Ws[r][c] = *(const float4*)&W[(size_t)(bn + r) * K + k0 + c];
    }
    __syncthreads();
#pragma unroll
    for (int kk = 0; kk < 32; kk += 4) {
      float4 av[4], wv[4];
#pragma unroll
      for (int i = 0; i < 4; ++i) av[i] = *(const float4*)&As[ty * 4 + i][kk];
#pragma unroll
      for (int j = 0; j < 4; ++j) wv[j] = *(const float4*)&Ws[tx + 16 * j][kk];
#pragma unroll
      for (int i = 0; i < 4; ++i)
#pragma unroll
        for (int j = 0; j < 4; ++j)
          acc[i][j] += av[i].x * wv[j].x + av[i].y * wv[j].y +
                       av[i].z * wv[j].z + av[i].w * wv[j].w;
    }
  }

#pragma unroll
  for (int i = 0; i < 4; ++i) {
    int row = bm + ty * 4 + i;
#pragma unroll
    for (int j = 0; j < 4; ++j) {
      int col = bn + tx + 16 * j;
      C[(size_t)row * N + col] = acc[i][j] + bias[col];
    }
  }
}

// ---------------------------------------------------------------------------
// Per-(b,h,e) max |K_e| over keys — feeds the provable bf16-error margin.
// ---------------------------------------------------------------------------
__global__ __launch_bounds__(256) void kemax_kernel(
    const float* __restrict__ Kf, float* __restrict__ kemax)
{
  const int bh = blockIdx.x;
  const int b = bh >> 3, h = bh & 7;
  const int e = threadIdx.x & 63, chunk = threadIdx.x >> 6;
  const float* base = Kf + ((size_t)b * SEQ_L) * D_MODEL + h * HEAD_E + e;
  float mx = 0.f;
  for (int k = chunk * 512; k < chunk * 512 + 512; ++k)
    mx = fmaxf(mx, fabsf(base[(size_t)k * D_MODEL]));
  __shared__ float red[4][64];
  red[chunk][e] = mx;
  __syncthreads();
  if (threadIdx.x < 64) {
    float m0 = fmaxf(fmaxf(red[0][threadIdx.x], red[1][threadIdx.x]),
                     fmaxf(red[2][threadIdx.x], red[3][threadIdx.x]));
    kemax[bh * 64 + threadIdx.x] = m0;
  }
}

// ---------------------------------------------------------------------------
// Main ProbSparse attention v12 — lean path.  Threshold moved to
// mu + 1.863*sigma (count ~64): margin-capture stays ~136 << CCAP so the
// punt rate is ~0.5% (was 40% at 1.707 — capture overflowed).
// ---------------------------------------------------------------------------
__global__ __launch_bounds__(512) void attn_main(
    const float* __restrict__ Qf, const float* __restrict__ Kf,
    const float* __restrict__ Vf,
    const unsigned short* __restrict__ Qh, const unsigned short* __restrict__ Kh,
    const float* __restrict__ kemax, float* __restrict__ AO,
    int* __restrict__ nflag, int* __restrict__ flagged)
{
  __shared__ __half  S[16][SP];          // 65600 B approx scores
  __shared__ short   cis2[8][CCAP];      // captured candidate indices
  __shared__ float   cvs[8][64];         // exact candidates (post bisect)
  __shared__ short   cis[8][64];
  __shared__ float   qrowL[16][64];      // f32 q rows (hoisted)
  __shared__ float   kemaxL[64];

  const int t    = threadIdx.x;
  const int w    = t >> 6;
  const int l    = t & 63;

  // XCD-affine decode
  const int wg   = blockIdx.x;
  const int xcd  = wg & 7;
  const int idx  = wg >> 3;
  const int bh   = xcd + 8 * (idx >> 7);
  const int qblk = idx & 127;
  const int b    = bh >> 3, h = bh & 7;
  const int q0   = qblk << 4;
  const size_t rowbase = (size_t)b * SEQ_L;

  if (t < 64) kemaxL[t] = kemax[bh * 64 + t];

  // hoist both q-row loads (latency overlaps the MFMA scan)
  {
    const float* qb = Qf + (rowbase + q0 + 2 * w) * D_MODEL + h * HEAD_E;
    qrowL[2 * w][l]     = qb[l];
    qrowL[2 * w + 1][l] = qb[D_MODEL + l];
  }

  // ---- MFMA score scan: wave w covers keys [w*256, w*256+256) ----
  {
    const int lo16 = l & 15, grp = l >> 4;
    const unsigned short* qrow =
        Qh + (rowbase + q0 + lo16) * D_MODEL + h * HEAD_E;
    bf16x8 a0 = *(const bf16x8*)&qrow[grp * 8];
    bf16x8 a1 = *(const bf16x8*)&qrow[32 + grp * 8];

    const int kbase = w * 256;
#pragma unroll
    for (int kt = 0; kt < 4; ++kt) {
#pragma unroll
      for (int kc = 0; kc < 4; ++kc) {
        const int key0 = kbase + kt * 64 + kc * 16 + lo16;
        const unsigned short* krow =
            Kh + (rowbase + key0) * D_MODEL + h * HEAD_E;
        bf16x8 b0 = *(const bf16x8*)&krow[grp * 8];
        bf16x8 b1 = *(const bf16x8*)&krow[32 + grp * 8];
        f32x4 acc = {0.f, 0.f, 0.f, 0.f};
        acc = __builtin_amdgcn_mfma_f32_16x16x32_bf16(a0, b0, acc, 0, 0, 0);
        acc = __builtin_amdgcn_mfma_f32_16x16x32_bf16(a1, b1, acc, 0, 0, 0);
#pragma unroll
        for (int r = 0; r < 4; ++r)
          S[grp * 4 + r][key0] = __float2half(acc[r] * 0.125f);
      }
    }
  }
  __syncthreads();

  // ---- selection: wave w handles queries 2w, 2w+1 ----
  for (int qq = 0; qq < 2; ++qq) {
    const int q   = 2 * w + qq;
    const int qid = bh * SEQ_L + q0 + q;

    float v[32];
#pragma unroll
    for (int j = 0; j < 32; ++j) v[j] = __half2float(S[q][(j << 6) + l]);

    // fused max / mean / var reduce
    float m = v[0], s1 = 0.f, s2 = 0.f;
#pragma unroll
    for (int j = 0; j < 32; ++j) {
      m = fmaxf(m, v[j]); s1 += v[j]; s2 += v[j] * v[j];
    }
#pragma unroll
    for (int off = 1; off < 64; off <<= 1) {
      m  = fmaxf(m, __shfl_xor(m, off));
      s1 += __shfl_xor(s1, off);
      s2 += __shfl_xor(s2, off);
    }
    const float mu = s1 * (1.0f / 2048.0f);
    const float sg = sqrtf(fmaxf(s2 * (1.0f / 2048.0f) - mu * mu, 0.f));
    const float lo = mu + 1.863f * sg;   // targets count ~ 64

    // ONE verify countge
    int C = 0;
#pragma unroll
    for (int j = 0; j < 32; ++j) C += (v[j] >= lo) ? 1 : 0;
#pragma unroll
    for (int off = 1; off < 64; off <<= 1) C += __shfl_xor(C, off);

    bool punt = (C < 40) | (C > 176);
    int base = 0;
    if (!punt) {
      // provable margin capture (unchanged constants)
      float red = fabsf(qrowL[q][l]) * kemaxL[l];
#pragma unroll
      for (int off = 1; off < 64; off <<= 1) red += __shfl_xor(red, off);
      const float lo2 = lo - (red * 0.0025f + 0.008f);
#pragma unroll
      for (int j = 0; j < 32; ++j) {
        bool in = (v[j] >= lo2);
        unsigned long long mk = __ballot(in);
        if (in) {
          int pos = base + (int)__popcll(mk & ((1ull << l) - 1ull));
          if (pos < CCAP) cis2[w][pos] = (short)((j << 6) | l);
        }
        base += (int)__popcll(mk);
      }
      punt = (base > CCAP);
    }
    if (punt) {
      if (l == 0) { int p = atomicAdd(nflag, 1); flagged[p] = qid; }
      continue;
    }

    // ---- exact f32 rescore of captured candidates (3 per lane) ----
    const int count2 = base;
    const int i0 = l, i1 = 64 + l, i2 = 128 + l;
    const int idx0 = (i0 < count2) ? (int)cis2[w][i0] : 0;
    const int idx1 = (i1 < count2) ? (int)cis2[w][i1] : 0;
    const int idx2 = (i2 < count2) ? (int)cis2[w][i2] : 0;
    float e0 = -3.0e38f, e1 = -3.0e38f, e2 = -3.0e38f;
    {
      const float* kr0 = Kf + (rowbase + idx0) * D_MODEL + h * HEAD_E;
      const float* kr1 = Kf + (rowbase + idx1) * D_MODEL + h * HEAD_E;
      const float* kr2 = Kf + (rowbase + idx2) * D_MODEL + h * HEAD_E;
      float r0 = 0.f, r1 = 0.f, r2 = 0.f;
#pragma unroll
      for (int e4 = 0; e4 < 16; ++e4) {
        float4 qv = *(const float4*)&qrowL[q][e4 * 4];
        float4 k0 = *(const float4*)&kr0[e4 * 4];
        float4 k1 = *(const float4*)&kr1[e4 * 4];
        float4 k2 = *(const float4*)&kr2[e4 * 4];
        r0 += qv.x * k0.x + qv.y * k0.y + qv.z * k0.z + qv.w * k0.w;
        r1 += qv.x * k1.x + qv.y * k1.y + qv.z * k1.z + qv.w * k1.w;
        r2 += qv.x * k2.x + qv.y * k2.y + qv.z * k2.z + qv.w * k2.w;
      }
      if (i0 < count2) e0 = r0 * 0.125f;
      if (i1 < count2) e1 = r1 * 0.125f;
      if (i2 < count2) e2 = r2 * 0.125f;
    }

    // exact bisect to count in [40, 64]
    float hiv = fmaxf(fmaxf(e0, e1), e2);
    float lov = fminf(fminf((i0 < count2) ? e0 : 3.0e38f,
                            (i1 < count2) ? e1 : 3.0e38f),
                            (i2 < count2) ? e2 : 3.0e38f);
#pragma unroll
    for (int off = 1; off < 64; off <<= 1) {
      hiv = fmaxf(hiv, __shfl_xor(hiv, off));
      lov = fminf(lov, __shfl_xor(lov, off));
    }
    lov -= 1e-3f;
    for (int it = 0; it < 30; ++it) {
      int c = (int)__popcll(__ballot(e0 >= lov)) +
              (int)__popcll(__ballot(e1 >= lov)) +
              (int)__popcll(__ballot(e2 >= lov));
      if (c <= 64) break;
      float mid = 0.5f * (lov + hiv);
      int cm = (int)__popcll(__ballot(e0 >= mid)) +
               (int)__popcll(__ballot(e1 >= mid)) +
               (int)__popcll(__ballot(e2 >= mid));
      if (cm >= 40) lov = mid; else hiv = mid;
    }

    // compact exact-selected into cvs/cis (key order preserved)
    int C2;
    {
      bool in0 = (e0 >= lov);
      bool in1 = (e1 >= lov);
      bool in2 = (e2 >= lov);
      unsigned long long m0 = __ballot(in0);
      unsigned long long m1 = __ballot(in1);
      unsigned long long m2 = __ballot(in2);
      int tot0 = (int)__popcll(m0), tot1 = (int)__popcll(m1);
      if (in0) {
        int p = (int)__popcll(m0 & ((1ull << l) - 1ull));
        if (p < 64) { cvs[w][p] = e0; cis[w][p] = (short)idx0; }
      }
      if (in1) {
        int p = tot0 + (int)__popcll(m1 & ((1ull << l) - 1ull));
        if (p < 64) { cvs[w][p] = e1; cis[w][p] = (short)idx1; }
      }
      if (in2) {
        int p = tot0 + tot1 + (int)__popcll(m2 & ((1ull << l) - 1ull));
        if (p < 64) { cvs[w][p] = e2; cis[w][p] = (short)idx2; }
      }
      int tot = tot0 + tot1 + (int)__popcll(m2);
      C2 = (tot < 64) ? tot : 64;
    }

    float cval = (l < C2) ? cvs[w][l] : -3.0e38f;
    int   cidx = (l < C2) ? (int)cis[w][l] : (2 * SEQ_L + l);

    // bitonic sort 64: value desc, index asc
#pragma unroll
    for (int sz = 2; sz <= 64; sz <<= 1) {
#pragma unroll
      for (int st = sz >> 1; st >= 1; st >>= 1) {
        float ov = __shfl_xor(cval, st);
        int   oi = __shfl_xor(cidx, st);
        bool ob    = (ov > cval) || ((ov == cval) && (oi < cidx));
        bool dir   = ((l & sz) == 0);
        bool lower = ((l & st) == 0);
        if (ob == (lower == dir)) { cval = ov; cidx = oi; }
      }
    }

    const float m_ex = __shfl(cval, 0);
    const float v37  = __shfl(cval, 37);
    const float v38  = __shfl(cval, 38);
    if (v37 - v38 < 2e-5f) {           // tight boundary -> fixup
      if (l == 0) { int p = atomicAdd(nflag, 1); flagged[p] = qid; }
      continue;
    }

    float myw = (l < KSEL) ? __expf(cval - m_ex) : 0.f;
    float psum = myw;
#pragma unroll
    for (int off = 1; off < 64; off <<= 1) psum += __shfl_xor(psum, off);
    const float inv = 1.0f / psum;

    // ---- PV: branchless, 8 gather loads in flight per batch ----
    const float* Vb = Vf + rowbase * D_MODEL + h * HEAD_E;
    float acc = 0.f;
    for (int j0 = 0; j0 < 40; j0 += 8) {
      float wv8[8]; const float* vp8[8];
#pragma unroll
      for (int u = 0; u < 8; ++u) {
        wv8[u] = __shfl(myw, j0 + u);
        int sj = __shfl(cidx, j0 + u) & (SEQ_L - 1);
        vp8[u] = Vb + (size_t)sj * D_MODEL + l;
      }
      float vv8[8];
#pragma unroll
      for (int u = 0; u < 8; ++u) vv8[u] = *vp8[u];
#pragma unroll
      for (int u = 0; u < 8; ++u) acc = fmaf(wv8[u], vv8[u], acc);
    }
    AO[(rowbase + q0 + q) * D_MODEL + h * HEAD_E + l] = acc * inv;
  }
}

// ---------------------------------------------------------------------------
// Fixup v2: coalesced + scratch-free. One wave per query (~0.5% of queries).
// K-scan via swizzled LDS tiles; scores staged in LDS Sf (keeps v[] static).
// f64 rescore fully cooperative: coalesced loads + wave reduces.
// ---------------------------------------------------------------------------
__global__ __launch_bounds__(64) void attn_fixup(
    const float* __restrict__ Qf, const float* __restrict__ Kf,
    const float* __restrict__ Vf,
    const float* __restrict__ x,
    const float* __restrict__ Wq, const float* __restrict__ bq,
    const float* __restrict__ Wk, const float* __restrict__ bk,
    float* __restrict__ AO,
    const int* __restrict__ nflag, const int* __restrict__ flagged)
{
  __shared__ float  Kt[64 * 64];    // swizzled K tile, 16 KB
  __shared__ float  Sf[SEQ_L];      // exact f32 scores, 8 KB
  __shared__ float  qr[64];
  __shared__ double qdL[64];
  __shared__ float  cv[64];
  __shared__ int    ci[64];

  const int l = threadIdx.x;
  const int n = *nflag;

  for (int s = blockIdx.x; s < n; s += gridDim.x) {
    const int qid  = flagged[s];
    const int bh   = qid >> 11, qrow = qid & (SEQ_L - 1);
    const int b    = bh >> 3, h = bh & 7;
    const size_t rowbase = (size_t)b * SEQ_L;
    const float* Kb = Kf + rowbase * D_MODEL + h * HEAD_E;

    qr[l] = Qf[(rowbase + qrow) * D_MODEL + h * HEAD_E + l];
    __syncthreads();

    float4 q_r[16];
#pragma unroll
    for (int e4 = 0; e4 < 16; ++e4) q_r[e4] = *(const float4*)&qr[e4 * 4];

    // ---- exact f32 scan: 32 tiles of 64 keys, coalesced via LDS ----
    for (int ti = 0; ti < 32; ++ti) {
      __syncthreads();
#pragma unroll
      for (int i = 0; i < 16; ++i) {
        int f = l + (i << 6);
        int r = f >> 4, c4 = f & 15;
        ((float4*)Kt)[(r << 4) | (c4 ^ (r & 15))] =
            *(const float4*)&Kb[(size_t)((ti << 6) + r) * D_MODEL + (c4 << 2)];
      }
      __syncthreads();
      float a0 = 0.f, a1 = 0.f;
#pragma unroll
      for (int e4 = 0; e4 < 16; ++e4) {
        float4 kv = ((const float4*)Kt)[(l << 4) | (e4 ^ (l & 15))];
        if (e4 & 1) a1 += q_r[e4].x * kv.x + q_r[e4].y * kv.y +
                          q_r[e4].z * kv.z + q_r[e4].w * kv.w;
        else        a0 += q_r[e4].x * kv.x + q_r[e4].y * kv.y +
                          q_r[e4].z * kv.z + q_r[e4].w * kv.w;
      }
      Sf[(ti << 6) + l] = (a0 + a1) * 0.125f;
    }

    float v[32];
#pragma unroll
    for (int j = 0; j < 32; ++j) v[j] = Sf[(j << 6) + l];

    auto countge = [&](float T) -> int {
      int c = 0;
#pragma unroll
      for (int j = 0; j < 32; ++j) c += (v[j] >= T) ? 1 : 0;
#pragma unroll
      for (int off = 1; off < 64; off <<= 1) c += __shfl_xor(c, off);
      return c;
    };

    // bisect to count in [40, 64]
    float hiv = v[0], lov = v[0];
#pragma unroll
    for (int j = 1; j < 32; ++j) { hiv = fmaxf(hiv, v[j]); lov = fminf(lov, v[j]); }
#pragma unroll
    for (int off = 1; off < 64; off <<= 1) {
      hiv = fmaxf(hiv, __shfl_xor(hiv, off));
      lov = fminf(lov, __shfl_xor(lov, off));
    }
    lov -= 1e-3f;
    for (int it = 0; it < 30; ++it) {
      int c = countge(lov);
      if (c <= 64) break;
      float mid = 0.5f * (lov + hiv);
      int cm = countge(mid);
      if (cm >= 40) lov = mid; else hiv = mid;
    }

    // compact candidates (key order), cap 64
    int bb = 0;
#pragma unroll
    for (int j = 0; j < 32; ++j) {
      bool in = (v[j] >= lov);
      unsigned long long mk = __ballot(in);
      if (in) {
        int pos = bb + (int)__popcll(mk & ((1ull << l) - 1ull));
        if (pos < 64) { cv[pos] = v[j]; ci[pos] = (j << 6) + l; }
      }
      bb += (int)__popcll(mk);
    }
    const int C2 = (bb < 64) ? bb : 64;
    __syncthreads();
    const int cidx = (l < C2) ? ci[l] : (2 * SEQ_L + l);

    // ---- f64 rescore, cooperative/coalesced ----
    // qdL[he] = Wq[h*64+he] . x[qrow] + bq  (exact f64)
    const float* xr = x + (rowbase + qrow) * D_MODEL;
    float xreg[8];
#pragma unroll
    for (int jc = 0; jc < 8; ++jc) xreg[jc] = xr[(jc << 6) + l];
    for (int he = 0; he < 64; ++he) {
      const float* wqr = Wq + (size_t)(h * HEAD_E + he) * D_MODEL;
      double p = 0.0;
#pragma unroll
      for (int jc = 0; jc < 8; ++jc)
        p += (double)wqr[(jc << 6) + l] * (double)xreg[jc];
#pragma unroll
      for (int off = 1; off < 64; off <<= 1) p += __shfl_xor(p, off);
      if (l == 0) qdL[he] = p + (double)bq[h * HEAD_E + he];
    }
    __syncthreads();

    // u_j (j = jc*64+l) = sum_e qdL[e] * Wk[h*64+e][j]   (coalesced over l)
    double u[8] = {};
    for (int e = 0; e < 64; ++e) {
      const double qde = qdL[e];
      const float* wkr = Wk + (size_t)(h * HEAD_E + e) * D_MODEL + l;
#pragma unroll
      for (int jc = 0; jc < 8; ++jc)
        u[jc] += qde * (double)wkr[jc << 6];
    }

    // qkb = sum_e qdL[e] * bk[h*64+e]
    double qkb = qdL[l] * (double)bk[h * HEAD_E + l];
#pragma unroll
    for (int off = 1; off < 64; off <<= 1) qkb += __shfl_xor(qkb, off);

    // per-candidate s_c = (qkb + sum_j u_j * x[c][j]) * 0.125
    double d = -1.0e300;
    for (int c = 0; c < 64; ++c) {
      int row = (c < C2) ? ci[c] : 0;
      const float* xc = x + (rowbase + row) * D_MODEL + l;
      double p = 0.0;
#pragma unroll
      for (int jc = 0; jc < 8; ++jc)
        p += u[jc] * (double)xc[jc << 6];
#pragma unroll
      for (int off = 1; off < 64; off <<= 1) p += __shfl_xor(p, off);
      if (l == c && c < C2) d = (qkb + p) * 0.125;
    }

    int myi = (l < C2) ? cidx : (2 * SEQ_L + l);
    double mxd = -1.0e300; int rank = 0;
    for (int j = 0; j < 64; ++j) {
      double dj = __shfl(d, j);
      int    ij = __shfl(myi, j);
      if (dj > mxd) mxd = dj;
      rank += (dj > d) || ((dj == d) && (ij < myi));
    }
    float myw = (l < C2 && rank < KSEL) ? __expf((float)(d - mxd)) : 0.f;

    float psum = myw;
#pragma unroll
    for (int off = 1; off < 64; off <<= 1) psum += __shfl_xor(psum, off);
    const float inv = 1.0f / psum;

    // PV
    const float* Vb = Vf + rowbase * D_MODEL + h * HEAD_E;
    float acc = 0.f;
    for (int j0 = 0; j0 < 64; j0 += 8) {
      float wv8[8]; const float* vp8[8];
#pragma unroll
      for (int u8 = 0; u8 < 8; ++u8) {
        wv8[u8] = __shfl(myw, j0 + u8);
        int sj = __shfl(cidx, j0 + u8) & (SEQ_L - 1);
        vp8[u8] = Vb + (size_t)sj * D_MODEL + l;
      }
      float vv8[8];
#pragma unroll
      for (int u8 = 0; u8 < 8; ++u8) vv8[u8] = *vp8[u8];
#pragma unroll
      for (int u8 = 0; u8 < 8; ++u8) acc = fmaf(wv8[u8], vv8[u8], acc);
    }
    AO[(rowbase + qrow) * D_MODEL + h * HEAD_E + l] = acc * inv;
    __syncthreads();   // protect shared buffers before next iteration
  }
}

// ---------------------------------------------------------------------------
extern "C" void kernel_launch(void* const* d_in, const int* in_sizes, int n_in,
                              void* d_out, int out_size, void* d_ws, size_t ws_size,
                              hipStream_t stream) {
  const float* x  = (const float*)d_in[0];
  const float* Wq = (const float*)d_in[1];
  const float* bq = (const float*)d_in[2];
  const float* Wk = (const float*)d_in[3];
  const float* bk = (const float*)d_in[4];
  const float* Wv = (const float*)d_in[5];
  const float* bv = (const float*)d_in[6];
  const float* Wo = (const float*)d_in[7];
  const float* bo = (const float*)d_in[8];
  float* out = (float*)d_out;

  char* ws = (char*)d_ws;
  const size_t MATB = (size_t)M_ROWS * D_MODEL * 4;  // 8 MB
  float* Qf = (float*)ws;
  float* Kf = (float*)(ws + MATB);
  float* Vf = (float*)(ws + 2 * MATB);
  float* AO = (float*)(ws + 3 * MATB);
  unsigned short* Qh = (unsigned short*)(ws + 4 * MATB);            // 4 MB
  unsigned short* Kh = (unsigned short*)(ws + 4 * MATB + MATB / 2); // 4 MB
  float* kemax = (float*)(ws + 5 * MATB);                           // 4 KB
  int* nflag   = (int*)(ws + 5 * MATB + 4096);
  int* flagged = (int*)(ws + 5 * MATB + 8192);                      // 128 KB

  hipMemsetAsync(nflag, 0, 64, stream);

  dim3 qkvgrid(D_MODEL / 64, M_ROWS / 64, 3);
  gemm_qkv_kernel<<<qkvgrid, 256, 0, stream>>>(
      x, Wq, bq, Wk, bk, Wv, bv, Qf, Kf, Vf, Qh, Kh);

  kemax_kernel<<<dim3(BATCH * N_HEADS), 256, 0, stream>>>(Kf, kemax);

  attn_main<<<dim3(SEQ_L / 16 * BATCH * N_HEADS), 512, 0, stream>>>(
      Qf, Kf, Vf, Qh, Kh, kemax, AO, nflag, flagged);

  attn_fixup<<<dim3(2048), 64, 0, stream>>>(
      Qf, Kf, Vf, x, Wq, bq, Wk, bk, AO, nflag, flagged);

  dim3 ggrid(D_MODEL / 64, M_ROWS / 64);
  gemm_bias_kernel<<<ggrid, 256, 0, stream>>>(AO, Wo, bo, out, M_ROWS, D_MODEL, D_MODEL);
}

// Round 13
// 1242.365 us; speedup vs baseline: 3.1014x; 1.0010x over previous
//
#include <hip/hip_runtime.h>
#include <hip/hip_fp16.h>
#include <cstdint>
#include <cstddef>

#define D_MODEL 512
#define N_HEADS 8
#define HEAD_E  64
#define SEQ_L   2048
#define BATCH   2
#define KSEL    38            // int(5*log(2048)) = 38
#define M_ROWS  (BATCH*SEQ_L) // 4096
#define SP      2050          // S row stride (f16)
#define CCAP    192           // candidate cap (3 per lane); overflow -> fixup

typedef short bf16x8 __attribute__((ext_vector_type(8)));
typedef float f32x4  __attribute__((ext_vector_type(4)));

static __device__ __forceinline__ unsigned short f2bf(float x) {
  uint32_t u = __float_as_uint(x);
  return (unsigned short)((u + 0x7FFF + ((u >> 16) & 1)) >> 16);  // RNE
}

// ---------------------------------------------------------------------------
// Fused QKV f32 GEMM: z=0:Q, z=1:K, z=2:V. C = x @ W.T + b. Q,K emit bf16 too.
// ---------------------------------------------------------------------------
__global__ __launch_bounds__(256) void gemm_qkv_kernel(
    const float* __restrict__ A,
    const float* __restrict__ Wq, const float* __restrict__ bq,
    const float* __restrict__ Wk, const float* __restrict__ bk,
    const float* __restrict__ Wv, const float* __restrict__ bv,
    float* __restrict__ Qf, float* __restrict__ Kf, float* __restrict__ Vf,
    unsigned short* __restrict__ Qh, unsigned short* __restrict__ Kh)
{
  const int z = blockIdx.z;
  const float* W    = (z == 0) ? Wq : ((z == 1) ? Wk : Wv);
  const float* bias = (z == 0) ? bq : ((z == 1) ? bk : bv);
  float* C          = (z == 0) ? Qf : ((z == 1) ? Kf : Vf);
  unsigned short* Ch = (z == 0) ? Qh : ((z == 1) ? Kh : nullptr);

  __shared__ float As[64][36];
  __shared__ float Ws[64][36];
  const int t  = threadIdx.x;
  const int tx = t & 15, ty = t >> 4;
  const int bm = blockIdx.y << 6, bn = blockIdx.x << 6;

  float acc[4][4] = {};

  for (int k0 = 0; k0 < D_MODEL; k0 += 32) {
    __syncthreads();
#pragma unroll
    for (int i = 0; i < 2; ++i) {
      int f = t + (i << 8);
      int r = f >> 3, c = (f & 7) << 2;
      *(float4*)&As[r][c] = *(const float4*)&A[(size_t)(bm + r) * D_MODEL + k0 + c];
      *(float4*)&Ws[r][c] = *(const float4*)&W[(size_t)(bn + r) * D_MODEL + k0 + c];
    }
    __syncthreads();
#pragma unroll
    for (int kk = 0; kk < 32; kk += 4) {
      float4 av[4], wv[4];
#pragma unroll
      for (int i = 0; i < 4; ++i) av[i] = *(const float4*)&As[ty * 4 + i][kk];
#pragma unroll
      for (int j = 0; j < 4; ++j) wv[j] = *(const float4*)&Ws[tx + 16 * j][kk];
#pragma unroll
      for (int i = 0; i < 4; ++i)
#pragma unroll
        for (int j = 0; j < 4; ++j)
          acc[i][j] += av[i].x * wv[j].x + av[i].y * wv[j].y +
                       av[i].z * wv[j].z + av[i].w * wv[j].w;
    }
  }

#pragma unroll
  for (int i = 0; i < 4; ++i) {
    int row = bm + ty * 4 + i;
#pragma unroll
    for (int j = 0; j < 4; ++j) {
      int col = bn + tx + 16 * j;
      float v = acc[i][j] + bias[col];
      size_t idx = (size_t)row * D_MODEL + col;
      C[idx] = v;
      if (Ch) Ch[idx] = f2bf(v);
    }
  }
}

// ---------------------------------------------------------------------------
// f32 GEMM (output projection): C = A @ W.T + b
// ---------------------------------------------------------------------------
__global__ __launch_bounds__(256) void gemm_bias_kernel(
    const float* __restrict__ A, const float* __restrict__ W,
    const float* __restrict__ bias, float* __restrict__ C,
    int M, int N, int K)
{
  __shared__ float As[64][36];
  __shared__ float Ws[64][36];
  const int t  = threadIdx.x;
  const int tx = t & 15, ty = t >> 4;
  const int bm = blockIdx.y << 6, bn = blockIdx.x << 6;

  float acc[4][4] = {};

  for (int k0 = 0; k0 < K; k0 += 32) {
    __syncthreads();
#pragma unroll
    for (int i = 0; i < 2; ++i) {
      int f = t + (i << 8);
      int r = f >> 3, c = (f & 7) << 2;
      *(float4*)&As[r][c] = *(const float4*)&A[(size_t)(bm + r) * K + k0 + c];
      *(float4*)&Ws[r][c] = *(const float4*)&W[(size_t)(bn + r) * K + k0 + c];
    }
    __syncthreads();
#pragma unroll
    for (int kk = 0; kk < 32; kk += 4) {
      float4 av[4], wv[4];
#pragma unroll
      for (int i = 0; i < 4; ++i) av[i] = *(const float4*)&As[ty * 4 + i][kk];
#pragma unroll
      for (int j = 0; j < 4; ++j) wv[j] = *(const float4*)&Ws[tx + 16 * j][kk];
#pragma unroll
      for (int i = 0; i < 4; ++i)
#pragma unroll
        for (int j = 0; j < 4; ++j)
          acc[i][j] += av[i].x * wv[j].x + av[i].y * wv[j].y +
                       av[i].z * wv[j].z + av[i].w * wv[j].w;
    }
  }

#pragma unroll
  for (int i = 0; i < 4; ++i) {
    int row = bm + ty * 4 + i;
#pragma unroll
    for (int j = 0; j < 4; ++j) {
      int col = bn + tx + 16 * j;
      C[(size_t)row * N + col] = acc[i][j] + bias[col];
    }
  }
}

// ---------------------------------------------------------------------------
// Per-(b,h,e) max |K_e| over keys — feeds the provable bf16-error margin.
// ---------------------------------------------------------------------------
__global__ __launch_bounds__(256) void kemax_kernel(
    const float* __restrict__ Kf, float* __restrict__ kemax)
{
  const int bh = blockIdx.x;
  const int b = bh >> 3, h = bh & 7;
  const int e = threadIdx.x & 63, chunk = threadIdx.x >> 6;
  const float* base = Kf + ((size_t)b * SEQ_L) * D_MODEL + h * HEAD_E + e;
  float mx = 0.f;
  for (int k = chunk * 512; k < chunk * 512 + 512; ++k)
    mx = fmaxf(mx, fabsf(base[(size_t)k * D_MODEL]));
  __shared__ float red[4][64];
  red[chunk][e] = mx;
  __syncthreads();
  if (threadIdx.x < 64) {
    float m0 = fmaxf(fmaxf(red[0][threadIdx.x], red[1][threadIdx.x]),
                     fmaxf(red[2][threadIdx.x], red[3][threadIdx.x]));
    kemax[bh * 64 + threadIdx.x] = m0;
  }
}

// ---------------------------------------------------------------------------
// Main ProbSparse attention v12 — lean path.  Threshold moved to
// mu + 1.863*sigma (count ~64): margin-capture stays ~136 << CCAP so the
// punt rate is ~0.5% (was 40% at 1.707 — capture overflowed).
// ---------------------------------------------------------------------------
__global__ __launch_bounds__(512) void attn_main(
    const float* __restrict__ Qf, const float* __restrict__ Kf,
    const float* __restrict__ Vf,
    const unsigned short* __restrict__ Qh, const unsigned short* __restrict__ Kh,
    const float* __restrict__ kemax, float* __restrict__ AO,
    int* __restrict__ nflag, int* __restrict__ flagged)
{
  __shared__ __half  S[16][SP];          // 65600 B approx scores
  __shared__ short   cis2[8][CCAP];      // captured candidate indices
  __shared__ float   cvs[8][64];         // exact candidates (post bisect)
  __shared__ short   cis[8][64];
  __shared__ float   qrowL[16][64];      // f32 q rows (hoisted)
  __shared__ float   kemaxL[64];

  const int t    = threadIdx.x;
  const int w    = t >> 6;
  const int l    = t & 63;

  // XCD-affine decode
  const int wg   = blockIdx.x;
  const int xcd  = wg & 7;
  const int idx  = wg >> 3;
  const int bh   = xcd + 8 * (idx >> 7);
  const int qblk = idx & 127;
  const int b    = bh >> 3, h = bh & 7;
  const int q0   = qblk << 4;
  const size_t rowbase = (size_t)b * SEQ_L;

  if (t < 64) kemaxL[t] = kemax[bh * 64 + t];

  // hoist both q-row loads (latency overlaps the MFMA scan)
  {
    const float* qb = Qf + (rowbase + q0 + 2 * w) * D_MODEL + h * HEAD_E;
    qrowL[2 * w][l]     = qb[l];
    qrowL[2 * w + 1][l] = qb[D_MODEL + l];
  }

  // ---- MFMA score scan: wave w covers keys [w*256, w*256+256) ----
  {
    const int lo16 = l & 15, grp = l >> 4;
    const unsigned short* qrow =
        Qh + (rowbase + q0 + lo16) * D_MODEL + h * HEAD_E;
    bf16x8 a0 = *(const bf16x8*)&qrow[grp * 8];
    bf16x8 a1 = *(const bf16x8*)&qrow[32 + grp * 8];

    const int kbase = w * 256;
#pragma unroll
    for (int kt = 0; kt < 4; ++kt) {
#pragma unroll
      for (int kc = 0; kc < 4; ++kc) {
        const int key0 = kbase + kt * 64 + kc * 16 + lo16;
        const unsigned short* krow =
            Kh + (rowbase + key0) * D_MODEL + h * HEAD_E;
        bf16x8 b0 = *(const bf16x8*)&krow[grp * 8];
        bf16x8 b1 = *(const bf16x8*)&krow[32 + grp * 8];
        f32x4 acc = {0.f, 0.f, 0.f, 0.f};
        acc = __builtin_amdgcn_mfma_f32_16x16x32_bf16(a0, b0, acc, 0, 0, 0);
        acc = __builtin_amdgcn_mfma_f32_16x16x32_bf16(a1, b1, acc, 0, 0, 0);
#pragma unroll
        for (int r = 0; r < 4; ++r)
          S[grp * 4 + r][key0] = __float2half(acc[r] * 0.125f);
      }
    }
  }
  __syncthreads();

  // ---- selection: wave w handles queries 2w, 2w+1 ----
  for (int qq = 0; qq < 2; ++qq) {
    const int q   = 2 * w + qq;
    const int qid = bh * SEQ_L + q0 + q;

    float v[32];
#pragma unroll
    for (int j = 0; j < 32; ++j) v[j] = __half2float(S[q][(j << 6) + l]);

    // fused max / mean / var reduce
    float m = v[0], s1 = 0.f, s2 = 0.f;
#pragma unroll
    for (int j = 0; j < 32; ++j) {
      m = fmaxf(m, v[j]); s1 += v[j]; s2 += v[j] * v[j];
    }
#pragma unroll
    for (int off = 1; off < 64; off <<= 1) {
      m  = fmaxf(m, __shfl_xor(m, off));
      s1 += __shfl_xor(s1, off);
      s2 += __shfl_xor(s2, off);
    }
    const float mu = s1 * (1.0f / 2048.0f);
    const float sg = sqrtf(fmaxf(s2 * (1.0f / 2048.0f) - mu * mu, 0.f));
    const float lo = mu + 1.863f * sg;   // targets count ~ 64

    // ONE verify countge
    int C = 0;
#pragma unroll
    for (int j = 0; j < 32; ++j) C += (v[j] >= lo) ? 1 : 0;
#pragma unroll
    for (int off = 1; off < 64; off <<= 1) C += __shfl_xor(C, off);

    bool punt = (C < 40) | (C > 176);
    int base = 0;
    if (!punt) {
      // provable margin capture (unchanged constants)
      float red = fabsf(qrowL[q][l]) * kemaxL[l];
#pragma unroll
      for (int off = 1; off < 64; off <<= 1) red += __shfl_xor(red, off);
      const float lo2 = lo - (red * 0.0025f + 0.008f);
#pragma unroll
      for (int j = 0; j < 32; ++j) {
        bool in = (v[j] >= lo2);
        unsigned long long mk = __ballot(in);
        if (in) {
          int pos = base + (int)__popcll(mk & ((1ull << l) - 1ull));
          if (pos < CCAP) cis2[w][pos] = (short)((j << 6) | l);
        }
        base += (int)__popcll(mk);
      }
      punt = (base > CCAP);
    }
    if (punt) {
      if (l == 0) { int p = atomicAdd(nflag, 1); flagged[p] = qid; }
      continue;
    }

    // ---- exact f32 rescore of captured candidates (3 per lane) ----
    const int count2 = base;
    const int i0 = l, i1 = 64 + l, i2 = 128 + l;
    const int idx0 = (i0 < count2) ? (int)cis2[w][i0] : 0;
    const int idx1 = (i1 < count2) ? (int)cis2[w][i1] : 0;
    const int idx2 = (i2 < count2) ? (int)cis2[w][i2] : 0;
    float e0 = -3.0e38f, e1 = -3.0e38f, e2 = -3.0e38f;
    {
      const float* kr0 = Kf + (rowbase + idx0) * D_MODEL + h * HEAD_E;
      const float* kr1 = Kf + (rowbase + idx1) * D_MODEL + h * HEAD_E;
      const float* kr2 = Kf + (rowbase + idx2) * D_MODEL + h * HEAD_E;
      float r0 = 0.f, r1 = 0.f, r2 = 0.f;
#pragma unroll
      for (int e4 = 0; e4 < 16; ++e4) {
        float4 qv = *(const float4*)&qrowL[q][e4 * 4];
        float4 k0 = *(const float4*)&kr0[e4 * 4];
        float4 k1 = *(const float4*)&kr1[e4 * 4];
        float4 k2 = *(const float4*)&kr2[e4 * 4];
        r0 += qv.x * k0.x + qv.y * k0.y + qv.z * k0.z + qv.w * k0.w;
        r1 += qv.x * k1.x + qv.y * k1.y + qv.z * k1.z + qv.w * k1.w;
        r2 += qv.x * k2.x + qv.y * k2.y + qv.z * k2.z + qv.w * k2.w;
      }
      if (i0 < count2) e0 = r0 * 0.125f;
      if (i1 < count2) e1 = r1 * 0.125f;
      if (i2 < count2) e2 = r2 * 0.125f;
    }

    // exact bisect to count in [40, 64]
    float hiv = fmaxf(fmaxf(e0, e1), e2);
    float lov = fminf(fminf((i0 < count2) ? e0 : 3.0e38f,
                            (i1 < count2) ? e1 : 3.0e38f),
                            (i2 < count2) ? e2 : 3.0e38f);
#pragma unroll
    for (int off = 1; off < 64; off <<= 1) {
      hiv = fmaxf(hiv, __shfl_xor(hiv, off));
      lov = fminf(lov, __shfl_xor(lov, off));
    }
    lov -= 1e-3f;
    for (int it = 0; it < 30; ++it) {
      int c = (int)__popcll(__ballot(e0 >= lov)) +
              (int)__popcll(__ballot(e1 >= lov)) +
              (int)__popcll(__ballot(e2 >= lov));
      if (c <= 64) break;
      float mid = 0.5f * (lov + hiv);
      int cm = (int)__popcll(__ballot(e0 >= mid)) +
               (int)__popcll(__ballot(e1 >= mid)) +
               (int)__popcll(__ballot(e2 >= mid));
      if (cm >= 40) lov = mid; else hiv = mid;
    }

    // compact exact-selected into cvs/cis (key order preserved)
    int C2;
    {
      bool in0 = (e0 >= lov);
      bool in1 = (e1 >= lov);
      bool in2 = (e2 >= lov);
      unsigned long long m0 = __ballot(in0);
      unsigned long long m1 = __ballot(in1);
      unsigned long long m2 = __ballot(in2);
      int tot0 = (int)__popcll(m0), tot1 = (int)__popcll(m1);
      if (in0) {
        int p = (int)__popcll(m0 & ((1ull << l) - 1ull));
        if (p < 64) { cvs[w][p] = e0; cis[w][p] = (short)idx0; }
      }
      if (in1) {
        int p = tot0 + (int)__popcll(m1 & ((1ull << l) - 1ull));
        if (p < 64) { cvs[w][p] = e1; cis[w][p] = (short)idx1; }
      }
      if (in2) {
        int p = tot0 + tot1 + (int)__popcll(m2 & ((1ull << l) - 1ull));
        if (p < 64) { cvs[w][p] = e2; cis[w][p] = (short)idx2; }
      }
      int tot = tot0 + tot1 + (int)__popcll(m2);
      C2 = (tot < 64) ? tot : 64;
    }

    float cval = (l < C2) ? cvs[w][l] : -3.0e38f;
    int   cidx = (l < C2) ? (int)cis[w][l] : (2 * SEQ_L + l);

    // bitonic sort 64: value desc, index asc
#pragma unroll
    for (int sz = 2; sz <= 64; sz <<= 1) {
#pragma unroll
      for (int st = sz >> 1; st >= 1; st >>= 1) {
        float ov = __shfl_xor(cval, st);
        int   oi = __shfl_xor(cidx, st);
        bool ob    = (ov > cval) || ((ov == cval) && (oi < cidx));
        bool dir   = ((l & sz) == 0);
        bool lower = ((l & st) == 0);
        if (ob == (lower == dir)) { cval = ov; cidx = oi; }
      }
    }

    const float m_ex = __shfl(cval, 0);
    const float v37  = __shfl(cval, 37);
    const float v38  = __shfl(cval, 38);
    if (v37 - v38 < 2e-5f) {           // tight boundary -> fixup
      if (l == 0) { int p = atomicAdd(nflag, 1); flagged[p] = qid; }
      continue;
    }

    float myw = (l < KSEL) ? __expf(cval - m_ex) : 0.f;
    float psum = myw;
#pragma unroll
    for (int off = 1; off < 64; off <<= 1) psum += __shfl_xor(psum, off);
    const float inv = 1.0f / psum;

    // ---- PV: branchless, 8 gather loads in flight per batch ----
    const float* Vb = Vf + rowbase * D_MODEL + h * HEAD_E;
    float acc = 0.f;
    for (int j0 = 0; j0 < 40; j0 += 8) {
      float wv8[8]; const float* vp8[8];
#pragma unroll
      for (int u = 0; u < 8; ++u) {
        wv8[u] = __shfl(myw, j0 + u);
        int sj = __shfl(cidx, j0 + u) & (SEQ_L - 1);
        vp8[u] = Vb + (size_t)sj * D_MODEL + l;
      }
      float vv8[8];
#pragma unroll
      for (int u = 0; u < 8; ++u) vv8[u] = *vp8[u];
#pragma unroll
      for (int u = 0; u < 8; ++u) acc = fmaf(wv8[u], vv8[u], acc);
    }
    AO[(rowbase + q0 + q) * D_MODEL + h * HEAD_E + l] = acc * inv;
  }
}

// ---------------------------------------------------------------------------
// Fixup v2: coalesced + scratch-free. One wave per query (~0.5% of queries).
// K-scan via swizzled LDS tiles; scores staged in LDS Sf (keeps v[] static).
// f64 rescore fully cooperative: coalesced loads + wave reduces.
// ---------------------------------------------------------------------------
__global__ __launch_bounds__(64) void attn_fixup(
    const float* __restrict__ Qf, const float* __restrict__ Kf,
    const float* __restrict__ Vf,
    const float* __restrict__ x,
    const float* __restrict__ Wq, const float* __restrict__ bq,
    const float* __restrict__ Wk, const float* __restrict__ bk,
    float* __restrict__ AO,
    const int* __restrict__ nflag, const int* __restrict__ flagged)
{
  __shared__ float  Kt[64 * 64];    // swizzled K tile, 16 KB
  __shared__ float  Sf[SEQ_L];      // exact f32 scores, 8 KB
  __shared__ float  qr[64];
  __shared__ double qdL[64];
  __shared__ float  cv[64];
  __shared__ int    ci[64];

  const int l = threadIdx.x;
  const int n = *nflag;

  for (int s = blockIdx.x; s < n; s += gridDim.x) {
    const int qid  = flagged[s];
    const int bh   = qid >> 11, qrow = qid & (SEQ_L - 1);
    const int b    = bh >> 3, h = bh & 7;
    const size_t rowbase = (size_t)b * SEQ_L;
    const float* Kb = Kf + rowbase * D_MODEL + h * HEAD_E;

    qr[l] = Qf[(rowbase + qrow) * D_MODEL + h * HEAD_E + l];
    __syncthreads();

    float4 q_r[16];
#pragma unroll
    for (int e4 = 0; e4 < 16; ++e4) q_r[e4] = *(const float4*)&qr[e4 * 4];

    // ---- exact f32 scan: 32 tiles of 64 keys, coalesced via LDS ----
    for (int ti = 0; ti < 32; ++ti) {
      __syncthreads();
#pragma unroll
      for (int i = 0; i < 16; ++i) {
        int f = l + (i << 6);
        int r = f >> 4, c4 = f & 15;
        ((float4*)Kt)[(r << 4) | (c4 ^ (r & 15))] =
            *(const float4*)&Kb[(size_t)((ti << 6) + r) * D_MODEL + (c4 << 2)];
      }
      __syncthreads();
      float a0 = 0.f, a1 = 0.f;
#pragma unroll
      for (int e4 = 0; e4 < 16; ++e4) {
        float4 kv = ((const float4*)Kt)[(l << 4) | (e4 ^ (l & 15))];
        if (e4 & 1) a1 += q_r[e4].x * kv.x + q_r[e4].y * kv.y +
                          q_r[e4].z * kv.z + q_r[e4].w * kv.w;
        else        a0 += q_r[e4].x * kv.x + q_r[e4].y * kv.y +
                          q_r[e4].z * kv.z + q_r[e4].w * kv.w;
      }
      Sf[(ti << 6) + l] = (a0 + a1) * 0.125f;
    }

    float v[32];
#pragma unroll
    for (int j = 0; j < 32; ++j) v[j] = Sf[(j << 6) + l];

    auto countge = [&](float T) -> int {
      int c = 0;
#pragma unroll
      for (int j = 0; j < 32; ++j) c += (v[j] >= T) ? 1 : 0;
#pragma unroll
      for (int off = 1; off < 64; off <<= 1) c += __shfl_xor(c, off);
      return c;
    };

    // bisect to count in [40, 64]
    float hiv = v[0], lov = v[0];
#pragma unroll
    for (int j = 1; j < 32; ++j) { hiv = fmaxf(hiv, v[j]); lov = fminf(lov, v[j]); }
#pragma unroll
    for (int off = 1; off < 64; off <<= 1) {
      hiv = fmaxf(hiv, __shfl_xor(hiv, off));
      lov = fminf(lov, __shfl_xor(lov, off));
    }
    lov -= 1e-3f;
    for (int it = 0; it < 30; ++it) {
      int c = countge(lov);
      if (c <= 64) break;
      float mid = 0.5f * (lov + hiv);
      int cm = countge(mid);
      if (cm >= 40) lov = mid; else hiv = mid;
    }

    // compact candidates (key order), cap 64
    int bb = 0;
#pragma unroll
    for (int j = 0; j < 32; ++j) {
      bool in = (v[j] >= lov);
      unsigned long long mk = __ballot(in);
      if (in) {
        int pos = bb + (int)__popcll(mk & ((1ull << l) - 1ull));
        if (pos < 64) { cv[pos] = v[j]; ci[pos] = (j << 6) + l; }
      }
      bb += (int)__popcll(mk);
    }
    const int C2 = (bb < 64) ? bb : 64;
    __syncthreads();
    const int cidx = (l < C2) ? ci[l] : (2 * SEQ_L + l);

    // ---- f64 rescore, cooperative/coalesced ----
    // qdL[he] = Wq[h*64+he] . x[qrow] + bq  (exact f64)
    const float* xr = x + (rowbase + qrow) * D_MODEL;
    float xreg[8];
#pragma unroll
    for (int jc = 0; jc < 8; ++jc) xreg[jc] = xr[(jc << 6) + l];
    for (int he = 0; he < 64; ++he) {
      const float* wqr = Wq + (size_t)(h * HEAD_E + he) * D_MODEL;
      double p = 0.0;
#pragma unroll
      for (int jc = 0; jc < 8; ++jc)
        p += (double)wqr[(jc << 6) + l] * (double)xreg[jc];
#pragma unroll
      for (int off = 1; off < 64; off <<= 1) p += __shfl_xor(p, off);
      if (l == 0) qdL[he] = p + (double)bq[h * HEAD_E + he];
    }
    __syncthreads();

    // u_j (j = jc*64+l) = sum_e qdL[e] * Wk[h*64+e][j]   (coalesced over l)
    double u[8] = {};
    for (int e = 0; e < 64; ++e) {
      const double qde = qdL[e];
      const float* wkr = Wk + (size_t)(h * HEAD_E + e) * D_MODEL + l;
#pragma unroll
      for (int jc = 0; jc < 8; ++jc)
        u[jc] += qde * (double)wkr[jc << 6];
    }

    // qkb = sum_e qdL[e] * bk[h*64+e]
    double qkb = qdL[l] * (double)bk[h * HEAD_E + l];
#pragma unroll
    for (int off = 1; off < 64; off <<= 1) qkb += __shfl_xor(qkb, off);

    // per-candidate s_c = (qkb + sum_j u_j * x[c][j]) * 0.125
    double d = -1.0e300;
    for (int c = 0; c < 64; ++c) {
      int row = (c < C2) ? ci[c] : 0;
      const float* xc = x + (rowbase + row) * D_MODEL + l;
      double p = 0.0;
#pragma unroll
      for (int jc = 0; jc < 8; ++jc)
        p += u[jc] * (double)xc[jc << 6];
#pragma unroll
      for (int off = 1; off < 64; off <<= 1) p += __shfl_xor(p, off);
      if (l == c && c < C2) d = (qkb + p) * 0.125;
    }

    int myi = (l < C2) ? cidx : (2 * SEQ_L + l);
    double mxd = -1.0e300; int rank = 0;
    for (int j = 0; j < 64; ++j) {
      double dj = __shfl(d, j);
      int    ij = __shfl(myi, j);
      if (dj > mxd) mxd = dj;
      rank += (dj > d) || ((dj == d) && (ij < myi));
    }
    float myw = (l < C2 && rank < KSEL) ? __expf((float)(d - mxd)) : 0.f;

    float psum = myw;
#pragma unroll
    for (int off = 1; off < 64; off <<= 1) psum += __shfl_xor(psum, off);
    const float inv = 1.0f / psum;

    // PV
    const float* Vb = Vf + rowbase * D_MODEL + h * HEAD_E;
    float acc = 0.f;
    for (int j0 = 0; j0 < 64; j0 += 8) {
      float wv8[8]; const float* vp8[8];
#pragma unroll
      for (int u8 = 0; u8 < 8; ++u8) {
        wv8[u8] = __shfl(myw, j0 + u8);
        int sj = __shfl(cidx, j0 + u8) & (SEQ_L - 1);
        vp8[u8] = Vb + (size_t)sj * D_MODEL + l;
      }
      float vv8[8];
#pragma unroll
      for (int u8 = 0; u8 < 8; ++u8) vv8[u8] = *vp8[u8];
#pragma unroll
      for (int u8 = 0; u8 < 8; ++u8) acc = fmaf(wv8[u8], vv8[u8], acc);
    }
    AO[(rowbase + qrow) * D_MODEL + h * HEAD_E + l] = acc * inv;
    __syncthreads();   // protect shared buffers before next iteration
  }
}

// ---------------------------------------------------------------------------
extern "C" void kernel_launch(void* const* d_in, const int* in_sizes, int n_in,
                              void* d_out, int out_size, void* d_ws, size_t ws_size,
                              hipStream_t stream) {
  const float* x  = (const float*)d_in[0];
  const float* Wq = (const float*)d_in[1];
  const float* bq = (const float*)d_in[2];
  const float* Wk = (const float*)d_in[3];
  const float* bk = (const float*)d_in[4];
  const float* Wv = (const float*)d_in[5];
  const float* bv = (const float*)d_in[6];
  const float* Wo = (const float*)d_in[7];
  const float* bo = (const float*)d_in[8];
  float* out = (float*)d_out;

  char* ws = (char*)d_ws;
  const size_t MATB = (size_t)M_ROWS * D_MODEL * 4;  // 8 MB
  float* Qf = (float*)ws;
  float* Kf = (float*)(ws + MATB);
  float* Vf = (float*)(ws + 2 * MATB);
  float* AO = (float*)(ws + 3 * MATB);
  unsigned short* Qh = (unsigned short*)(ws + 4 * MATB);            // 4 MB
  unsigned short* Kh = (unsigned short*)(ws + 4 * MATB + MATB / 2); // 4 MB
  float* kemax = (float*)(ws + 5 * MATB);                           // 4 KB
  int* nflag   = (int*)(ws + 5 * MATB + 4096);
  int* flagged = (int*)(ws + 5 * MATB + 8192);                      // 128 KB

  hipMemsetAsync(nflag, 0, 64, stream);

  dim3 qkvgrid(D_MODEL / 64, M_ROWS / 64, 3);
  gemm_qkv_kernel<<<qkvgrid, 256, 0, stream>>>(
      x, Wq, bq, Wk, bk, Wv, bv, Qf, Kf, Vf, Qh, Kh);

  kemax_kernel<<<dim3(BATCH * N_HEADS), 256, 0, stream>>>(Kf, kemax);

  attn_main<<<dim3(SEQ_L / 16 * BATCH * N_HEADS), 512, 0, stream>>>(
      Qf, Kf, Vf, Qh, Kh, kemax, AO, nflag, flagged);

  attn_fixup<<<dim3(2048), 64, 0, stream>>>(
      Qf, Kf, Vf, x, Wq, bq, Wk, bk, AO, nflag, flagged);

  dim3 ggrid(D_MODEL / 64, M_ROWS / 64);
  gemm_bias_kernel<<<ggrid, 256, 0, stream>>>(AO, Wo, bo, out, M_ROWS, D_MODEL, D_MODEL);
}